// Round 9
// baseline (1276.214 us; speedup 1.0000x reference)
//
#include <hip/hip_runtime.h>
#include <stdint.h>

typedef unsigned short u16;
typedef __attribute__((ext_vector_type(8))) short short8;
typedef __attribute__((ext_vector_type(4))) float f32x4;

#define NE   8
#define DIN  2048
#define DOUT 8192
#define NTOK 16384

__device__ __forceinline__ u16 f2bf(float f) {
  uint32_t u = __builtin_bit_cast(uint32_t, f);
  u += 0x7FFFu + ((u >> 16) & 1u);   // RNE (inputs are finite normals)
  return (u16)(u >> 16);
}

__global__ __launch_bounds__(256) void cvt_f32_bf16(const float* __restrict__ src,
                                                    u16* __restrict__ dst, size_t n) {
  size_t i = ((size_t)blockIdx.x * 256 + threadIdx.x) * 8;
  const size_t stride = (size_t)gridDim.x * 256 * 8;
  for (; i < n; i += stride) {
    f32x4 a = *(const f32x4*)(src + i);
    f32x4 b = *(const f32x4*)(src + i + 4);
    short8 o;
    o[0] = (short)f2bf(a[0]); o[1] = (short)f2bf(a[1]);
    o[2] = (short)f2bf(a[2]); o[3] = (short)f2bf(a[3]);
    o[4] = (short)f2bf(b[0]); o[5] = (short)f2bf(b[1]);
    o[6] = (short)f2bf(b[2]); o[7] = (short)f2bf(b[3]);
    *(short8*)(dst + i) = o;
  }
}

#define GLOAD_LDS16(g, l) __builtin_amdgcn_global_load_lds( \
    (const __attribute__((address_space(1))) void*)(g),     \
    (__attribute__((address_space(3))) void*)(l), 16, 0, 0)

// ---------------------------------------------------------------------------
// r9 = r8's schedule (4 barriers/K-tile, balanced quadrant phases, 0-conflict
// swizzle) + FUSED W conversion: the 160 us cvt_w pre-pass is deleted; B is
// reg-staged from f32 W (2x dwordx4 -> f2bf -> swizzled ds_write_b128, same
// LDS bytes as before so the read path is untouched). A stays gload_lds from
// the 17 us bf16 X pre-pass. W f32 re-reads hit L2 (8 m-tile blocks sharing a
// 2 MB W-panel run adjacently per XCD), so net HBM traffic drops vs the
// cvt_w round-trip.
// vmcnt (mixed queue, per-tile issue order B0(4),A0(2),B1(4),A1(2)):
//   VMW(8)@ph2 drains B0 -> write; VMW(2)@ph3 drains B1 -> write;
//   VMW(0)+lgkmcnt(0)@ph4 publishes the whole next tile (loads are >=2
//   phases old => cheap drain; r2's just-issued-drain hazard gone, last
//   tile needs no special case).
// ---------------------------------------------------------------------------
__global__ __launch_bounds__(512, 2) void moe_gemm8(
    const u16* __restrict__ Xb, const float* __restrict__ Wf,
    const int* __restrict__ counts, const float* __restrict__ bias,
    float* __restrict__ C) {
  extern __shared__ u16 sm[];  // 65536 u16

  const int tid = threadIdx.x;
  const int l = tid & 63;
  const int wid = tid >> 6;      // 0..7
  const int wr = wid >> 2;       // 0..1  (M halves of 128)
  const int wc = wid & 3;        // 0..3  (N quarters of 64)

  // XCD-bijective swizzle: 2048 blocks, 256/XCD == tiles/expert => expert==XCD
  const int id = blockIdx.x;
  const int swz = (id & 7) * 256 + (id >> 3);
  const int e = swz >> 8;
  const int rem = swz & 255;
  const int tn = rem >> 3;       // 0..31 (8 consecutive blocks share B-panel)
  const int tm = rem & 7;        // 0..7

  int off = 0;
  for (int i = 0; i < e; ++i) off += counts[i];
  const int row0 = off + tm * 256;
  const int col0 = tn * 256;
  const size_t wbase = (size_t)e * DOUT * DIN + (size_t)col0 * DIN;

  // -- staging per-lane constants (pre-swizzled global source, linear dest)
  const int rl = l >> 2;                     // row within 16-row slice
  const int q = (l & 3) ^ ((l >> 3) & 3);    // source k-granule (inverse swz)
  const int s0 = wid * 2, s1 = s0 + 1;       // this wave's 2 slices of 16
  const u16* pA0 = Xb + (size_t)(row0 + s0 * 16 + rl) * DIN + q * 8;
  const u16* pA1 = Xb + (size_t)(row0 + s1 * 16 + rl) * DIN + q * 8;
  const float* pBf0 = Wf + wbase + (size_t)(s0 * 16 + rl) * DIN + q * 8;
  const float* pBf1 = Wf + wbase + (size_t)(s1 * 16 + rl) * DIN + q * 8;

  // -- fragment-read per-lane constants (16x16 layout, r3-verified swizzle)
  const int f0 = ((l & 15) >> 1) & 3;
  const int gph = (l >> 4) ^ f0;             // physical granule 0..3
  const int aoff = (wr * 128 + (l & 15)) * 32 + gph * 8;
  const int boff = (wc * 64 + (l & 15)) * 32 + gph * 8;

  f32x4 acc[8][4] = {};
  short8 a[4], b[4];
  f32x4 bs0[4], bs1[4];   // in-flight B f32 staging (kh0 / kh1), static idx

#define SMA(buf, kh) (sm + (buf) * 32768 + (kh) * 8192)
#define SMB(buf, kh) (sm + (buf) * 32768 + 16384 + (kh) * 8192)
#define STAGE_A(buf, kt, kh) do { const int ko = (kt) * 64 + (kh) * 32; \
    GLOAD_LDS16(pA0 + ko, SMA(buf, kh) + s0 * 512);                     \
    GLOAD_LDS16(pA1 + ko, SMA(buf, kh) + s1 * 512); } while (0)
#define BLD(arr, kt, kh) do { const int ko = (kt) * 64 + (kh) * 32; \
    arr[0] = *(const f32x4*)(pBf0 + ko);                            \
    arr[1] = *(const f32x4*)(pBf0 + ko + 4);                        \
    arr[2] = *(const f32x4*)(pBf1 + ko);                            \
    arr[3] = *(const f32x4*)(pBf1 + ko + 4); } while (0)
#define BWR(buf, kh, arr) do {                                           \
    short8 v0, v1;                                                       \
    _Pragma("unroll") for (int j = 0; j < 4; ++j) {                      \
      v0[j] = (short)f2bf(arr[0][j]); v0[4 + j] = (short)f2bf(arr[1][j]);\
      v1[j] = (short)f2bf(arr[2][j]); v1[4 + j] = (short)f2bf(arr[3][j]);\
    }                                                                    \
    *(short8*)(SMB(buf, kh) + (s0 * 16 + rl) * 32 + (l & 3) * 8) = v0;   \
    *(short8*)(SMB(buf, kh) + (s1 * 16 + rl) * 32 + (l & 3) * 8) = v1; } while (0)
#define RA4(buf, kh, mb) do { _Pragma("unroll") for (int mf = 0; mf < 4; ++mf) \
    a[mf] = *(const short8*)(SMA(buf, kh) + aoff + ((mb) + mf) * 512); } while (0)
#define RB4(buf, kh) do { _Pragma("unroll") for (int nf = 0; nf < 4; ++nf) \
    b[nf] = *(const short8*)(SMB(buf, kh) + boff + nf * 512); } while (0)
#define FENCE() asm volatile("" ::: "memory")
#define BAR() do { FENCE(); __builtin_amdgcn_s_barrier(); FENCE(); } while (0)
#define VMW(N) asm volatile("s_waitcnt vmcnt(" #N ")" ::: "memory")
#define LGKM0() asm volatile("s_waitcnt lgkmcnt(0)" ::: "memory")
#define MMQ(mb) do { __builtin_amdgcn_s_setprio(1);                                \
    _Pragma("unroll") for (int mf = 0; mf < 4; ++mf)                               \
      _Pragma("unroll") for (int nf = 0; nf < 4; ++nf)                             \
        acc[(mb) + mf][nf] =                                                       \
          __builtin_amdgcn_mfma_f32_16x16x32_bf16(a[mf], b[nf], acc[(mb) + mf][nf], 0, 0, 0); \
    __builtin_amdgcn_s_setprio(0); } while (0)

  const int NKT = DIN / 64;  // 32 K-tiles

  // prologue: tile 0. Issue order B0(4),B1(4),A0(2),A1(2); VMW(4) drains B.
  BLD(bs0, 0, 0); BLD(bs1, 0, 1);
  STAGE_A(0, 0, 0); STAGE_A(0, 0, 1);
  VMW(4);
  BWR(0, 0, bs0); BWR(0, 1, bs1);
  VMW(0); LGKM0();
  BAR();

  for (int kt = 0; kt < NKT; kt += 2) {
#define TILE(cur, nxt, t) do {                                          \
    const bool hn = (t) + 1 < NKT;                                      \
    /* ph1: kh0 m0-3 (8 reads) ; issue B0,A0 of next tile */            \
    RA4(cur, 0, 0); RB4(cur, 0);                                        \
    if (hn) { BLD(bs0, (t) + 1, 0); STAGE_A(nxt, (t) + 1, 0); }         \
    BAR(); MMQ(0);                                                      \
    /* ph2: kh0 m4-7 ; issue B1,A1 ; drain+write B0 */                  \
    RA4(cur, 0, 4);                                                     \
    if (hn) { BLD(bs1, (t) + 1, 1); STAGE_A(nxt, (t) + 1, 1);           \
              VMW(8); BWR(nxt, 0, bs0); }                               \
    BAR(); MMQ(4);                                                      \
    /* ph3: kh1 m0-3 ; drain+write B1 */                                \
    RA4(cur, 1, 0); RB4(cur, 1);                                        \
    if (hn) { VMW(2); BWR(nxt, 1, bs1); }                               \
    BAR(); MMQ(0);                                                      \
    /* ph4: kh1 m4-7 ; publish next tile (loads >=2 phases old) */      \
    RA4(cur, 1, 4);                                                     \
    if (hn) { VMW(0); LGKM0(); }                                        \
    BAR(); MMQ(4); } while (0)
    TILE(0, 1, kt);
    TILE(1, 0, kt + 1);
#undef TILE
  }

  // epilogue: C/D layout col=lane&15, row=(lane>>4)*4+j  [m89]
  const int rb = row0 + wr * 128 + ((l >> 4) << 2);
  const int cb = col0 + wc * 64 + (l & 15);
#pragma unroll
  for (int n = 0; n < 4; ++n) {
    const int col = cb + n * 16;
    const float bv = bias[e * DOUT + col];
#pragma unroll
    for (int m = 0; m < 8; ++m) {
      const int r = rb + m * 16;
#pragma unroll
      for (int j = 0; j < 4; ++j)
        C[(size_t)(r + j) * DOUT + col] = acc[m][n][j] + bv;
    }
  }
}

// ---------------------------------------------------------------------------
// Fallback (ws too small): fused fp32->bf16 staging, 128x128 m97 structure.
// ---------------------------------------------------------------------------
__global__ __launch_bounds__(256) void moe_gemm_fused(
    const float* __restrict__ Xf, const float* __restrict__ Wf,
    const int* __restrict__ counts, const float* __restrict__ bias,
    float* __restrict__ C) {
  __shared__ __align__(16) u16 lds[2][2][128 * 32];

  const int tid = threadIdx.x;
  const int lane = tid & 63;
  const int wid = tid >> 6;
  const int wr = wid >> 1;
  const int wc = wid & 1;

  const int id = blockIdx.x;
  const int swz = (id & 7) * ((int)gridDim.x >> 3) + (id >> 3);
  const int e = swz >> 10;
  const int rem = swz & 1023;
  const int tn = rem >> 4;
  const int tml = rem & 15;

  int off = 0;
  for (int i = 0; i < e; ++i) off += counts[i];
  const int row0 = off + tml * 128;
  const int col0 = tn * 128;
  const size_t wbase = (size_t)e * DOUT * DIN + (size_t)col0 * DIN;

  f32x4 acc[4][4] = {};

  auto stage = [&](int buf, int kt) {
#pragma unroll
    for (int s = 0; s < 2; ++s) {
      int i = s * 256 + tid;
      int r = i >> 2, c = i & 3;
      const float* sa = Xf + (size_t)(row0 + r) * DIN + kt * 32 + c * 8;
      const float* sb = Wf + wbase + (size_t)r * DIN + kt * 32 + c * 8;
      f32x4 a0 = *(const f32x4*)sa;
      f32x4 a1 = *(const f32x4*)(sa + 4);
      f32x4 b0 = *(const f32x4*)sb;
      f32x4 b1 = *(const f32x4*)(sb + 4);
      short8 va, vb;
#pragma unroll
      for (int j = 0; j < 4; ++j) {
        va[j] = (short)f2bf(a0[j]); va[j + 4] = (short)f2bf(a1[j]);
        vb[j] = (short)f2bf(b0[j]); vb[j + 4] = (short)f2bf(b1[j]);
      }
      *(short8*)&lds[buf][0][i * 8] = va;
      *(short8*)&lds[buf][1][i * 8] = vb;
    }
  };

  auto compute = [&](int buf) {
    const int kc = lane >> 4;
    const int rr = lane & 15;
    short8 a[4], b[4];
    const u16* lA = lds[buf][0];
    const u16* lB = lds[buf][1];
#pragma unroll
    for (int m = 0; m < 4; ++m)
      a[m] = *(const short8*)(lA + (wr * 64 + m * 16 + rr) * 32 + kc * 8);
#pragma unroll
    for (int n = 0; n < 4; ++n)
      b[n] = *(const short8*)(lB + (wc * 64 + n * 16 + rr) * 32 + kc * 8);
#pragma unroll
    for (int m = 0; m < 4; ++m)
#pragma unroll
      for (int n = 0; n < 4; ++n)
        acc[m][n] = __builtin_amdgcn_mfma_f32_16x16x32_bf16(a[m], b[n], acc[m][n], 0, 0, 0);
  };

  stage(0, 0);
  for (int kt = 0; kt < DIN / 32; ++kt) {
    __syncthreads();
    if (kt + 1 < DIN / 32) stage((kt + 1) & 1, kt + 1);
    compute(kt & 1);
  }

  const int rbase = row0 + wr * 64;
  const int cbase = col0 + wc * 64;
#pragma unroll
  for (int n = 0; n < 4; ++n) {
    const int col = cbase + n * 16 + (lane & 15);
    const float bv = bias[e * DOUT + col];
#pragma unroll
    for (int m = 0; m < 4; ++m) {
      const int r0 = rbase + m * 16 + (lane >> 4) * 4;
#pragma unroll
      for (int j = 0; j < 4; ++j)
        C[(size_t)(r0 + j) * DOUT + col] = acc[m][n][j] + bv;
    }
  }
}

extern "C" void kernel_launch(void* const* d_in, const int* in_sizes, int n_in,
                              void* d_out, int out_size, void* d_ws, size_t ws_size,
                              hipStream_t stream) {
  const float* inp = (const float*)d_in[0];
  const int* counts = (const int*)d_in[1];
  const float* weight = (const float*)d_in[2];
  const float* bias = (const float*)d_in[3];
  float* out = (float*)d_out;

  const size_t nx = (size_t)NTOK * DIN;
  const size_t need = nx * sizeof(u16);   // only X is pre-converted now

  if (ws_size >= need) {
    u16* xb = (u16*)d_ws;
    cvt_f32_bf16<<<1024, 256, 0, stream>>>(inp, xb, nx);
    const int grid = (NTOK / 256) * (DOUT / 256);  // 2048
    moe_gemm8<<<grid, 512, 131072, stream>>>(xb, weight, counts, bias, out);
  } else {
    const int grid = (NTOK / 128) * (DOUT / 128);  // 8192
    moe_gemm_fused<<<grid, 256, 0, stream>>>(inp, weight, counts, bias, out);
  }
}

// Round 10
// 800.789 us; speedup vs baseline: 1.5937x; 1.5937x over previous
//
#include <hip/hip_runtime.h>
#include <stdint.h>

typedef unsigned short u16;
typedef __attribute__((ext_vector_type(8))) short short8;
typedef __attribute__((ext_vector_type(4))) float f32x4;

#define NE   8
#define DIN  2048
#define DOUT 8192
#define NTOK 16384

__device__ __forceinline__ u16 f2bf(float f) {
  uint32_t u = __builtin_bit_cast(uint32_t, f);
  u += 0x7FFFu + ((u >> 16) & 1u);   // RNE (inputs are finite normals)
  return (u16)(u >> 16);
}

__global__ __launch_bounds__(256) void cvt_f32_bf16(const float* __restrict__ src,
                                                    u16* __restrict__ dst, size_t n) {
  size_t i = ((size_t)blockIdx.x * 256 + threadIdx.x) * 8;
  const size_t stride = (size_t)gridDim.x * 256 * 8;
  for (; i < n; i += stride) {
    f32x4 a = *(const f32x4*)(src + i);
    f32x4 b = *(const f32x4*)(src + i + 4);
    short8 o;
    o[0] = (short)f2bf(a[0]); o[1] = (short)f2bf(a[1]);
    o[2] = (short)f2bf(a[2]); o[3] = (short)f2bf(a[3]);
    o[4] = (short)f2bf(b[0]); o[5] = (short)f2bf(b[1]);
    o[6] = (short)f2bf(b[2]); o[7] = (short)f2bf(b[3]);
    *(short8*)(dst + i) = o;
  }
}

#define GLOAD_LDS16(g, l) __builtin_amdgcn_global_load_lds( \
    (const __attribute__((address_space(1))) void*)(g),     \
    (__attribute__((address_space(3))) void*)(l), 16, 0, 0)

// ---------------------------------------------------------------------------
// r10 = r8 (best verified: GEMM 585us, 0 conflicts) with barriers merged to
// the publish-minimal 2 per K-tile (r9's fused-W fully reverted).
// Region = [stage 2 halves (issue-earliest) ; 12 ds_reads ; MMQ(0) ; MMQ(4) ;
//           VMW(4) ; BAR]
//   R1(t): stage A0,B0(t+1); reads kh0; publish kh1(t)   at its BAR
//   R2(t): stage A1,B1(t+1); reads kh1; publish kh0(t+1) at its BAR
// Mechanism: only 2 convergence points/tile -> the 2 waves/SIMD can drift
// within a half-tile, overlapping one wave's ds_reads with the other's MFMA
// cluster (lockstep {all-read}/{all-MFMA} alternation was serializing the
// LDS and MFMA pipes: 2300cy + 2483cy ~= measured 5486cy/K-tile).
// vmcnt trace (steady queue 8): VMW(4)@R1 drains A1B1(cur) [1 region old];
// VMW(4)@R2 drains A0B0(next). Last tile R1: VMW(0) (r2 lesson: counted
// wait with nothing newly staged is a no-op race on kh1).
// No new registers (256/wave cap: acc=128 AGPR + ~128 VGPR; r6/r9 lesson).
// ---------------------------------------------------------------------------
__global__ __launch_bounds__(512, 2) void moe_gemm8(
    const u16* __restrict__ Xb, const u16* __restrict__ Wb,
    const int* __restrict__ counts, const float* __restrict__ bias,
    float* __restrict__ C) {
  extern __shared__ u16 sm[];  // 65536 u16

  const int tid = threadIdx.x;
  const int l = tid & 63;
  const int wid = tid >> 6;      // 0..7
  const int wr = wid >> 2;       // 0..1  (M halves of 128)
  const int wc = wid & 3;        // 0..3  (N quarters of 64)

  // XCD-bijective swizzle: 2048 blocks, 256/XCD == tiles/expert => expert==XCD
  const int id = blockIdx.x;
  const int swz = (id & 7) * 256 + (id >> 3);
  const int e = swz >> 8;
  const int rem = swz & 255;
  const int tn = rem >> 3;       // 0..31 (8 consecutive blocks share B-panel)
  const int tm = rem & 7;        // 0..7

  int off = 0;
  for (int i = 0; i < e; ++i) off += counts[i];
  const int row0 = off + tm * 256;
  const int col0 = tn * 256;
  const size_t wbase = (size_t)e * DOUT * DIN + (size_t)col0 * DIN;

  // -- staging per-lane constants (pre-swizzled global source, linear dest)
  const int rl = l >> 2;                     // row within 16-row slice
  const int q = (l & 3) ^ ((l >> 3) & 3);    // source k-granule (inverse swz)
  const int s0 = wid * 2, s1 = s0 + 1;       // this wave's 2 slices of 16
  const u16* pA0 = Xb + (size_t)(row0 + s0 * 16 + rl) * DIN + q * 8;
  const u16* pA1 = Xb + (size_t)(row0 + s1 * 16 + rl) * DIN + q * 8;
  const u16* pB0 = Wb + wbase + (size_t)(s0 * 16 + rl) * DIN + q * 8;
  const u16* pB1 = Wb + wbase + (size_t)(s1 * 16 + rl) * DIN + q * 8;

  // -- fragment-read per-lane constants (16x16 layout, r3-verified swizzle)
  const int f0 = ((l & 15) >> 1) & 3;
  const int gph = (l >> 4) ^ f0;             // physical granule 0..3
  const int aoff = (wr * 128 + (l & 15)) * 32 + gph * 8;
  const int boff = (wc * 64 + (l & 15)) * 32 + gph * 8;

  f32x4 acc[8][4] = {};
  short8 a[4], b[4];

#define SMA(buf, kh) (sm + (buf) * 32768 + (kh) * 8192)
#define SMB(buf, kh) (sm + (buf) * 32768 + 16384 + (kh) * 8192)
#define STAGE_A(buf, kt, kh) do { const int ko = (kt) * 64 + (kh) * 32; \
    GLOAD_LDS16(pA0 + ko, SMA(buf, kh) + s0 * 512);                     \
    GLOAD_LDS16(pA1 + ko, SMA(buf, kh) + s1 * 512); } while (0)
#define STAGE_B(buf, kt, kh) do { const int ko = (kt) * 64 + (kh) * 32; \
    GLOAD_LDS16(pB0 + ko, SMB(buf, kh) + s0 * 512);                     \
    GLOAD_LDS16(pB1 + ko, SMB(buf, kh) + s1 * 512); } while (0)
#define RA4(buf, kh, mb) do { _Pragma("unroll") for (int mf = 0; mf < 4; ++mf) \
    a[mf] = *(const short8*)(SMA(buf, kh) + aoff + ((mb) + mf) * 512); } while (0)
#define RB4(buf, kh) do { _Pragma("unroll") for (int nf = 0; nf < 4; ++nf) \
    b[nf] = *(const short8*)(SMB(buf, kh) + boff + nf * 512); } while (0)
#define FENCE() asm volatile("" ::: "memory")
#define BAR() do { FENCE(); __builtin_amdgcn_s_barrier(); FENCE(); } while (0)
#define VMW(N) asm volatile("s_waitcnt vmcnt(" #N ")" ::: "memory")
#define MMQ(mb) do { __builtin_amdgcn_s_setprio(1);                                \
    _Pragma("unroll") for (int mf = 0; mf < 4; ++mf)                               \
      _Pragma("unroll") for (int nf = 0; nf < 4; ++nf)                             \
        acc[(mb) + mf][nf] =                                                       \
          __builtin_amdgcn_mfma_f32_16x16x32_bf16(a[mf], b[nf], acc[(mb) + mf][nf], 0, 0, 0); \
    __builtin_amdgcn_s_setprio(0); } while (0)

  const int NKT = DIN / 64;  // 32 K-tiles

  // prologue: tile 0 staged (kh0 first); VMW(4) publishes kh0, kh1 in flight.
  STAGE_A(0, 0, 0); STAGE_B(0, 0, 0); STAGE_A(0, 0, 1); STAGE_B(0, 0, 1);
  VMW(4);
  BAR();

  for (int kt = 0; kt < NKT; kt += 2) {
#define TILE(cur, nxt, t) do {                                          \
    const bool hn = (t) + 1 < NKT;                                      \
    /* R1: stage A0,B0(t+1) earliest; consume kh0; publish kh1 */       \
    if (hn) { STAGE_A(nxt, (t) + 1, 0); STAGE_B(nxt, (t) + 1, 0); }     \
    RA4(cur, 0, 0); RB4(cur, 0);                                        \
    MMQ(0);                                                             \
    RA4(cur, 0, 4);                                                     \
    MMQ(4);                                                             \
    if (hn) VMW(4); else VMW(0);                                        \
    BAR();                                                              \
    /* R2: stage A1,B1(t+1); consume kh1; publish next kh0 */           \
    if (hn) { STAGE_A(nxt, (t) + 1, 1); STAGE_B(nxt, (t) + 1, 1); }     \
    RA4(cur, 1, 0); RB4(cur, 1);                                        \
    MMQ(0);                                                             \
    RA4(cur, 1, 4);                                                     \
    MMQ(4);                                                             \
    if (hn) VMW(4);                                                     \
    BAR(); } while (0)
    TILE(0, 1, kt);
    TILE(1, 0, kt + 1);
#undef TILE
  }

  // epilogue: C/D layout col=lane&15, row=(lane>>4)*4+j  [m89]
  const int rb = row0 + wr * 128 + ((l >> 4) << 2);
  const int cb = col0 + wc * 64 + (l & 15);
#pragma unroll
  for (int n = 0; n < 4; ++n) {
    const int col = cb + n * 16;
    const float bv = bias[e * DOUT + col];
#pragma unroll
    for (int m = 0; m < 8; ++m) {
      const int r = rb + m * 16;
#pragma unroll
      for (int j = 0; j < 4; ++j)
        C[(size_t)(r + j) * DOUT + col] = acc[m][n][j] + bv;
    }
  }
}

// ---------------------------------------------------------------------------
// Fallback (ws too small): fused fp32->bf16 staging, 128x128 m97 structure.
// ---------------------------------------------------------------------------
__global__ __launch_bounds__(256) void moe_gemm_fused(
    const float* __restrict__ Xf, const float* __restrict__ Wf,
    const int* __restrict__ counts, const float* __restrict__ bias,
    float* __restrict__ C) {
  __shared__ __align__(16) u16 lds[2][2][128 * 32];

  const int tid = threadIdx.x;
  const int lane = tid & 63;
  const int wid = tid >> 6;
  const int wr = wid >> 1;
  const int wc = wid & 1;

  const int id = blockIdx.x;
  const int swz = (id & 7) * ((int)gridDim.x >> 3) + (id >> 3);
  const int e = swz >> 10;
  const int rem = swz & 1023;
  const int tn = rem >> 4;
  const int tml = rem & 15;

  int off = 0;
  for (int i = 0; i < e; ++i) off += counts[i];
  const int row0 = off + tml * 128;
  const int col0 = tn * 128;
  const size_t wbase = (size_t)e * DOUT * DIN + (size_t)col0 * DIN;

  f32x4 acc[4][4] = {};

  auto stage = [&](int buf, int kt) {
#pragma unroll
    for (int s = 0; s < 2; ++s) {
      int i = s * 256 + tid;
      int r = i >> 2, c = i & 3;
      const float* sa = Xf + (size_t)(row0 + r) * DIN + kt * 32 + c * 8;
      const float* sb = Wf + wbase + (size_t)r * DIN + kt * 32 + c * 8;
      f32x4 a0 = *(const f32x4*)sa;
      f32x4 a1 = *(const f32x4*)(sa + 4);
      f32x4 b0 = *(const f32x4*)sb;
      f32x4 b1 = *(const f32x4*)(sb + 4);
      short8 va, vb;
#pragma unroll
      for (int j = 0; j < 4; ++j) {
        va[j] = (short)f2bf(a0[j]); va[j + 4] = (short)f2bf(a1[j]);
        vb[j] = (short)f2bf(b0[j]); vb[j + 4] = (short)f2bf(b1[j]);
      }
      *(short8*)&lds[buf][0][i * 8] = va;
      *(short8*)&lds[buf][1][i * 8] = vb;
    }
  };

  auto compute = [&](int buf) {
    const int kc = lane >> 4;
    const int rr = lane & 15;
    short8 a[4], b[4];
    const u16* lA = lds[buf][0];
    const u16* lB = lds[buf][1];
#pragma unroll
    for (int m = 0; m < 4; ++m)
      a[m] = *(const short8*)(lA + (wr * 64 + m * 16 + rr) * 32 + kc * 8);
#pragma unroll
    for (int n = 0; n < 4; ++n)
      b[n] = *(const short8*)(lB + (wc * 64 + n * 16 + rr) * 32 + kc * 8);
#pragma unroll
    for (int m = 0; m < 4; ++m)
#pragma unroll
      for (int n = 0; n < 4; ++n)
        acc[m][n] = __builtin_amdgcn_mfma_f32_16x16x32_bf16(a[m], b[n], acc[m][n], 0, 0, 0);
  };

  stage(0, 0);
  for (int kt = 0; kt < DIN / 32; ++kt) {
    __syncthreads();
    if (kt + 1 < DIN / 32) stage((kt + 1) & 1, kt + 1);
    compute(kt & 1);
  }

  const int rbase = row0 + wr * 64;
  const int cbase = col0 + wc * 64;
#pragma unroll
  for (int n = 0; n < 4; ++n) {
    const int col = cbase + n * 16 + (lane & 15);
    const float bv = bias[e * DOUT + col];
#pragma unroll
    for (int m = 0; m < 4; ++m) {
      const int r0 = rbase + m * 16 + (lane >> 4) * 4;
#pragma unroll
      for (int j = 0; j < 4; ++j)
        C[(size_t)(r0 + j) * DOUT + col] = acc[m][n][j] + bv;
    }
  }
}

extern "C" void kernel_launch(void* const* d_in, const int* in_sizes, int n_in,
                              void* d_out, int out_size, void* d_ws, size_t ws_size,
                              hipStream_t stream) {
  const float* inp = (const float*)d_in[0];
  const int* counts = (const int*)d_in[1];
  const float* weight = (const float*)d_in[2];
  const float* bias = (const float*)d_in[3];
  float* out = (float*)d_out;

  const size_t nx = (size_t)NTOK * DIN;
  const size_t nw = (size_t)NE * DOUT * DIN;
  const size_t need = (nx + nw) * sizeof(u16);

  if (ws_size >= need) {
    u16* xb = (u16*)d_ws;
    u16* wb = xb + nx;
    cvt_f32_bf16<<<2048, 256, 0, stream>>>(inp, xb, nx);
    cvt_f32_bf16<<<4096, 256, 0, stream>>>(weight, wb, nw);
    const int grid = (NTOK / 256) * (DOUT / 256);  // 2048
    moe_gemm8<<<grid, 512, 131072, stream>>>(xb, wb, counts, bias, out);
  } else {
    const int grid = (NTOK / 128) * (DOUT / 128);  // 8192
    moe_gemm_fused<<<grid, 256, 0, stream>>>(inp, weight, counts, bias, out);
  }
}

// Round 11
// 730.468 us; speedup vs baseline: 1.7471x; 1.0963x over previous
//
#include <hip/hip_runtime.h>
#include <stdint.h>

typedef unsigned short u16;
typedef __attribute__((ext_vector_type(8))) short short8;
typedef __attribute__((ext_vector_type(4))) float f32x4;

#define NE   8
#define DIN  2048
#define DOUT 8192
#define NTOK 16384

__device__ __forceinline__ u16 f2bf(float f) {
  uint32_t u = __builtin_bit_cast(uint32_t, f);
  u += 0x7FFFu + ((u >> 16) & 1u);   // RNE (inputs are finite normals)
  return (u16)(u >> 16);
}

__global__ __launch_bounds__(256) void cvt_f32_bf16(const float* __restrict__ src,
                                                    u16* __restrict__ dst, size_t n) {
  size_t i = ((size_t)blockIdx.x * 256 + threadIdx.x) * 8;
  const size_t stride = (size_t)gridDim.x * 256 * 8;
  for (; i < n; i += stride) {
    f32x4 a = *(const f32x4*)(src + i);
    f32x4 b = *(const f32x4*)(src + i + 4);
    short8 o;
    o[0] = (short)f2bf(a[0]); o[1] = (short)f2bf(a[1]);
    o[2] = (short)f2bf(a[2]); o[3] = (short)f2bf(a[3]);
    o[4] = (short)f2bf(b[0]); o[5] = (short)f2bf(b[1]);
    o[6] = (short)f2bf(b[2]); o[7] = (short)f2bf(b[3]);
    *(short8*)(dst + i) = o;
  }
}

#define GLOAD_LDS16(g, l) __builtin_amdgcn_global_load_lds( \
    (const __attribute__((address_space(1))) void*)(g),     \
    (__attribute__((address_space(3))) void*)(l), 16, 0, 0)

// ---------------------------------------------------------------------------
// r11 = r8's K-loop (verified best: 4 barriers/K-tile, balanced quadrant
// phases, 0-conflict swizzle, counted vmcnt w/ last-tile VMW(0)) + a
// COALESCED EPILOGUE: acc -> per-wave LDS scratch (free after K-loop) ->
// read back row-contiguous -> nontemporal global_store_dwordx4.
// Was: 128 scattered dword stores/thread (4x64B segs/instr, ~200us serial
// tail). Now: 32 coalesced dwordx4 (16 lanes = 256B per row segment), nt
// hint keeps the never-re-read C from evicting X/W panels out of L2.
// Per-wave double-buffered regions (2 x 16x68 f32 = 8704B/wave, 70KB total)
// avoid WAR stalls between m-frags. Bank math: writes 2-way (free).
// r10's 2-barrier merge REVERTED (regressed +6%: compiler re-bunched reads).
// ---------------------------------------------------------------------------
__global__ __launch_bounds__(512, 2) void moe_gemm8(
    const u16* __restrict__ Xb, const u16* __restrict__ Wb,
    const int* __restrict__ counts, const float* __restrict__ bias,
    float* __restrict__ C) {
  extern __shared__ u16 sm[];  // 65536 u16 = 128 KiB

  const int tid = threadIdx.x;
  const int l = tid & 63;
  const int wid = tid >> 6;      // 0..7
  const int wr = wid >> 2;       // 0..1  (M halves of 128)
  const int wc = wid & 3;        // 0..3  (N quarters of 64)

  // XCD-bijective swizzle: 2048 blocks, 256/XCD == tiles/expert => expert==XCD
  const int id = blockIdx.x;
  const int swz = (id & 7) * 256 + (id >> 3);
  const int e = swz >> 8;
  const int rem = swz & 255;
  const int tn = rem >> 3;       // 0..31 (8 consecutive blocks share B-panel)
  const int tm = rem & 7;        // 0..7

  int off = 0;
  for (int i = 0; i < e; ++i) off += counts[i];
  const int row0 = off + tm * 256;
  const int col0 = tn * 256;
  const size_t wbase = (size_t)e * DOUT * DIN + (size_t)col0 * DIN;

  // -- staging per-lane constants (pre-swizzled global source, linear dest)
  const int rl = l >> 2;                     // row within 16-row slice
  const int q = (l & 3) ^ ((l >> 3) & 3);    // source k-granule (inverse swz)
  const int s0 = wid * 2, s1 = s0 + 1;       // this wave's 2 slices of 16
  const u16* pA0 = Xb + (size_t)(row0 + s0 * 16 + rl) * DIN + q * 8;
  const u16* pA1 = Xb + (size_t)(row0 + s1 * 16 + rl) * DIN + q * 8;
  const u16* pB0 = Wb + wbase + (size_t)(s0 * 16 + rl) * DIN + q * 8;
  const u16* pB1 = Wb + wbase + (size_t)(s1 * 16 + rl) * DIN + q * 8;

  // -- fragment-read per-lane constants (16x16 layout, r3-verified swizzle)
  const int f0 = ((l & 15) >> 1) & 3;
  const int gph = (l >> 4) ^ f0;             // physical granule 0..3
  const int aoff = (wr * 128 + (l & 15)) * 32 + gph * 8;
  const int boff = (wc * 64 + (l & 15)) * 32 + gph * 8;

  f32x4 acc[8][4] = {};
  short8 a[4], b[4];

#define SMA(buf, kh) (sm + (buf) * 32768 + (kh) * 8192)
#define SMB(buf, kh) (sm + (buf) * 32768 + 16384 + (kh) * 8192)
#define STAGE_A(buf, kt, kh) do { const int ko = (kt) * 64 + (kh) * 32; \
    GLOAD_LDS16(pA0 + ko, SMA(buf, kh) + s0 * 512);                     \
    GLOAD_LDS16(pA1 + ko, SMA(buf, kh) + s1 * 512); } while (0)
#define STAGE_B(buf, kt, kh) do { const int ko = (kt) * 64 + (kh) * 32; \
    GLOAD_LDS16(pB0 + ko, SMB(buf, kh) + s0 * 512);                     \
    GLOAD_LDS16(pB1 + ko, SMB(buf, kh) + s1 * 512); } while (0)
#define RA4(buf, kh, mb) do { _Pragma("unroll") for (int mf = 0; mf < 4; ++mf) \
    a[mf] = *(const short8*)(SMA(buf, kh) + aoff + ((mb) + mf) * 512); } while (0)
#define RB4(buf, kh) do { _Pragma("unroll") for (int nf = 0; nf < 4; ++nf) \
    b[nf] = *(const short8*)(SMB(buf, kh) + boff + nf * 512); } while (0)
#define FENCE() asm volatile("" ::: "memory")
#define BAR() do { FENCE(); __builtin_amdgcn_s_barrier(); FENCE(); } while (0)
#define VMW(N) asm volatile("s_waitcnt vmcnt(" #N ")" ::: "memory")
#define LGKM0() asm volatile("s_waitcnt lgkmcnt(0)" ::: "memory")
#define MMQ(mb) do { __builtin_amdgcn_s_setprio(1);                                \
    _Pragma("unroll") for (int mf = 0; mf < 4; ++mf)                               \
      _Pragma("unroll") for (int nf = 0; nf < 4; ++nf)                             \
        acc[(mb) + mf][nf] =                                                       \
          __builtin_amdgcn_mfma_f32_16x16x32_bf16(a[mf], b[nf], acc[(mb) + mf][nf], 0, 0, 0); \
    __builtin_amdgcn_s_setprio(0); } while (0)

  const int NKT = DIN / 64;  // 32 K-tiles

  // prologue: tile 0 staged (kh0 first); VMW(4) publishes kh0, kh1 in flight.
  STAGE_A(0, 0, 0); STAGE_B(0, 0, 0); STAGE_A(0, 0, 1); STAGE_B(0, 0, 1);
  VMW(4);
  BAR();

  for (int kt = 0; kt < NKT; kt += 2) {
#define TILE(cur, nxt, t) do {                                          \
    const bool hn = (t) + 1 < NKT;                                      \
    /* ph1: kh0 m0-3 (8 reads pre-bar) */                               \
    RA4(cur, 0, 0); RB4(cur, 0);                                        \
    if (hn) STAGE_A(nxt, (t) + 1, 0);                                   \
    BAR(); MMQ(0);                                                      \
    /* ph2: kh0 m4-7 (4 reads) ; publish cur-kh1 */                     \
    RA4(cur, 0, 4);                                                     \
    if (hn) { STAGE_B(nxt, (t) + 1, 0); VMW(4); } else VMW(0);          \
    BAR(); MMQ(4);                                                      \
    /* ph3: kh1 m0-3 (8 reads) */                                       \
    RA4(cur, 1, 0); RB4(cur, 1);                                        \
    if (hn) STAGE_A(nxt, (t) + 1, 1);                                   \
    BAR(); MMQ(0);                                                      \
    /* ph4: kh1 m4-7 (4 reads) ; publish next-kh0 */                    \
    RA4(cur, 1, 4);                                                     \
    if (hn) { STAGE_B(nxt, (t) + 1, 1); VMW(4); }                       \
    BAR(); MMQ(4); } while (0)
    TILE(0, 1, kt);
    TILE(1, 0, kt + 1);
#undef TILE
  }

  // ---- epilogue: LDS repack -> coalesced nontemporal dwordx4 stores ----
  BAR();  // all K-loop LDS reads complete; LDS is now free scratch
  float* smf = (float*)sm;
  const int cbw = col0 + wc * 64;             // wave's 64-col span
  const int r0 = (l >> 4) << 2;               // acc row offset within frag
  const f32x4 bv4 = *(const f32x4*)(bias + (size_t)e * DOUT + cbw + (l & 15) * 4);

#pragma unroll
  for (int m = 0; m < 8; ++m) {
    float* eb = smf + (wid * 2 + (m & 1)) * 1088;   // 16x68 f32, dbuf'd
    // scatter acc frag into [16 rows][68 cols] (2-way banks = free)
#pragma unroll
    for (int n = 0; n < 4; ++n) {
      const int c = n * 16 + (l & 15);
#pragma unroll
      for (int j = 0; j < 4; ++j)
        eb[(r0 + j) * 68 + c] = acc[m][n][j];
    }
    LGKM0();  // own writes visible (wave-private region; also drains the
              // 2-iter-old reads of this region before reuse)
    const int rbm = row0 + wr * 128 + m * 16;
#pragma unroll
    for (int i = 0; i < 4; ++i) {
      const int row = i * 4 + (l >> 4);
      f32x4 v = *(const f32x4*)(eb + row * 68 + (l & 15) * 4);
      v = v + bv4;
      __builtin_nontemporal_store(
          v, (f32x4*)(C + (size_t)(rbm + row) * DOUT + cbw + (l & 15) * 4));
    }
  }
}

// ---------------------------------------------------------------------------
// Fallback (ws too small): fused fp32->bf16 staging, 128x128 m97 structure.
// ---------------------------------------------------------------------------
__global__ __launch_bounds__(256) void moe_gemm_fused(
    const float* __restrict__ Xf, const float* __restrict__ Wf,
    const int* __restrict__ counts, const float* __restrict__ bias,
    float* __restrict__ C) {
  __shared__ __align__(16) u16 lds[2][2][128 * 32];

  const int tid = threadIdx.x;
  const int lane = tid & 63;
  const int wid = tid >> 6;
  const int wr = wid >> 1;
  const int wc = wid & 1;

  const int id = blockIdx.x;
  const int swz = (id & 7) * ((int)gridDim.x >> 3) + (id >> 3);
  const int e = swz >> 10;
  const int rem = swz & 1023;
  const int tn = rem >> 4;
  const int tml = rem & 15;

  int off = 0;
  for (int i = 0; i < e; ++i) off += counts[i];
  const int row0 = off + tml * 128;
  const int col0 = tn * 128;
  const size_t wbase = (size_t)e * DOUT * DIN + (size_t)col0 * DIN;

  f32x4 acc[4][4] = {};

  auto stage = [&](int buf, int kt) {
#pragma unroll
    for (int s = 0; s < 2; ++s) {
      int i = s * 256 + tid;
      int r = i >> 2, c = i & 3;
      const float* sa = Xf + (size_t)(row0 + r) * DIN + kt * 32 + c * 8;
      const float* sb = Wf + wbase + (size_t)r * DIN + kt * 32 + c * 8;
      f32x4 a0 = *(const f32x4*)sa;
      f32x4 a1 = *(const f32x4*)(sa + 4);
      f32x4 b0 = *(const f32x4*)sb;
      f32x4 b1 = *(const f32x4*)(sb + 4);
      short8 va, vb;
#pragma unroll
      for (int j = 0; j < 4; ++j) {
        va[j] = (short)f2bf(a0[j]); va[j + 4] = (short)f2bf(a1[j]);
        vb[j] = (short)f2bf(b0[j]); vb[j + 4] = (short)f2bf(b1[j]);
      }
      *(short8*)&lds[buf][0][i * 8] = va;
      *(short8*)&lds[buf][1][i * 8] = vb;
    }
  };

  auto compute = [&](int buf) {
    const int kc = lane >> 4;
    const int rr = lane & 15;
    short8 a[4], b[4];
    const u16* lA = lds[buf][0];
    const u16* lB = lds[buf][1];
#pragma unroll
    for (int m = 0; m < 4; ++m)
      a[m] = *(const short8*)(lA + (wr * 64 + m * 16 + rr) * 32 + kc * 8);
#pragma unroll
    for (int n = 0; n < 4; ++n)
      b[n] = *(const short8*)(lB + (wc * 64 + n * 16 + rr) * 32 + kc * 8);
#pragma unroll
    for (int m = 0; m < 4; ++m)
#pragma unroll
      for (int n = 0; n < 4; ++n)
        acc[m][n] = __builtin_amdgcn_mfma_f32_16x16x32_bf16(a[m], b[n], acc[m][n], 0, 0, 0);
  };

  stage(0, 0);
  for (int kt = 0; kt < DIN / 32; ++kt) {
    __syncthreads();
    if (kt + 1 < DIN / 32) stage((kt + 1) & 1, kt + 1);
    compute(kt & 1);
  }

  const int rbase = row0 + wr * 64;
  const int cbase = col0 + wc * 64;
#pragma unroll
  for (int n = 0; n < 4; ++n) {
    const int col = cbase + n * 16 + (lane & 15);
    const float bv = bias[e * DOUT + col];
#pragma unroll
    for (int m = 0; m < 4; ++m) {
      const int r0 = rbase + m * 16 + (lane >> 4) * 4;
#pragma unroll
      for (int j = 0; j < 4; ++j)
        C[(size_t)(r0 + j) * DOUT + col] = acc[m][n][j] + bv;
    }
  }
}

extern "C" void kernel_launch(void* const* d_in, const int* in_sizes, int n_in,
                              void* d_out, int out_size, void* d_ws, size_t ws_size,
                              hipStream_t stream) {
  const float* inp = (const float*)d_in[0];
  const int* counts = (const int*)d_in[1];
  const float* weight = (const float*)d_in[2];
  const float* bias = (const float*)d_in[3];
  float* out = (float*)d_out;

  const size_t nx = (size_t)NTOK * DIN;
  const size_t nw = (size_t)NE * DOUT * DIN;
  const size_t need = (nx + nw) * sizeof(u16);

  if (ws_size >= need) {
    u16* xb = (u16*)d_ws;
    u16* wb = xb + nx;
    cvt_f32_bf16<<<2048, 256, 0, stream>>>(inp, xb, nx);
    cvt_f32_bf16<<<4096, 256, 0, stream>>>(weight, wb, nw);
    const int grid = (NTOK / 256) * (DOUT / 256);  // 2048
    moe_gemm8<<<grid, 512, 131072, stream>>>(xb, wb, counts, bias, out);
  } else {
    const int grid = (NTOK / 128) * (DOUT / 128);  // 8192
    moe_gemm_fused<<<grid, 256, 0, stream>>>(inp, weight, counts, bias, out);
  }
}